// Round 5
// baseline (99.959 us; speedup 1.0000x reference)
//
#include <hip/hip_runtime.h>
#include <hip/hip_bf16.h>

// Outputs (flat in d_out, all read back as float32 by the harness):
//   messages : [B, M, D] f32
//   upd_nodes: [B, M]    (int32 ref -> store as float values; -1.0f pad)
//   upd_ts   : [B, M]    f32
//
// Persistent-block pipeline: grid = B/EPB blocks; each block streams EPB
// events. While storing event e's [128,256] tile, the block prefetches the
// whole preamble of the next event (cid chain, membership scan, message
// float4) and stages its score row into the other half of a double-buffered
// LDS array. Next event's dependent-load latency hides under current stores;
// only the first preamble per block is exposed (kernel start, in parallel).

typedef float f32x4 __attribute__((ext_vector_type(4)));

constexpr int Dc  = 256;   // message dim (harness-fixed)
constexpr int Mc  = 128;   // max members (harness-fixed)
constexpr int EPB = 2;     // events per block

__global__ __launch_bounds__(256) void topk_main_spec(
    const float* __restrict__ unique_message,   // [B, 256]
    const float* __restrict__ member_score,     // [N_COMM, 128]
    const float* __restrict__ timestamps,       // [B]
    const int*   __restrict__ nodes,            // [B]
    const int*   __restrict__ node2community,   // [N_NODES]
    const int*   __restrict__ community2node,   // [N_COMM, 128]
    const int*   __restrict__ member_num,       // [N_COMM]
    const int*   __restrict__ community_index,  // [n_active]
    int n_active,
    float* __restrict__ out_msgs,               // [B, 128, 256]
    float* __restrict__ out_nodes,              // [B, 128] (float-encoded)
    float* __restrict__ out_ts)                 // [B, 128]
{
    const int tid  = threadIdx.x;
    const int lane = tid & 63;
    const int r    = tid >> 6;        // wave id 0..3
    const int nblk = gridDim.x;       // B / EPB

    __shared__ float s_score[2][Mc];

    int e = blockIdx.x;               // events: e, e+nblk, ...

    // ---- exposed preamble for the first event only ----
    int   cid  = node2community[nodes[e]];
    int   mnum = member_num[cid];
    float ts   = timestamps[e];
    f32x4 m4   = reinterpret_cast<const f32x4*>(
                     unique_message + (size_t)e * Dc)[lane];
    {
        bool f = false;
        for (int i = lane; i < n_active; i += 64)
            f |= (community_index[i] == cid);
        mnum = __any(f) ? mnum : 0;   // mlim folded into mnum
    }
    if (tid < Mc) s_score[0][tid] = member_score[(size_t)cid * Mc + tid];
    __syncthreads();

    int buf = 0;
#pragma unroll
    for (int ei = 0; ei < EPB; ++ei) {
        // ---- prefetch next event's preamble (hides under stores below) ----
        int   en = e, cidn = cid, mlimn = 0;
        float tsn = 0.0f;
        f32x4 m4n = m4;
        if (ei + 1 < EPB) {           // compile-time folded (full unroll)
            en   = e + nblk;
            cidn = node2community[nodes[en]];
            const int mnumn = member_num[cidn];
            tsn  = timestamps[en];
            m4n  = reinterpret_cast<const f32x4*>(
                       unique_message + (size_t)en * Dc)[lane];
            bool fn = false;
            for (int i = lane; i < n_active; i += 64)
                fn |= (community_index[i] == cidn);
            mlimn = __any(fn) ? mnumn : 0;
        }

        // ---- side outputs for current event (waves 0-1) ----
        if (tid < Mc) {
            const bool  valid = tid < mnum;
            const float vn = valid
                ? (float)community2node[(size_t)cid * Mc + tid] : -1.0f;
            __builtin_nontemporal_store(vn,  &out_nodes[(size_t)e * Mc + tid]);
            __builtin_nontemporal_store(valid ? ts : 0.0f,
                                        &out_ts[(size_t)e * Mc + tid]);
        }

        // ---- stage next event's scores into the other LDS buffer ----
        if (ei + 1 < EPB && tid < Mc)
            s_score[buf ^ 1][tid] = member_score[(size_t)cidn * Mc + tid];

        // ---- stream current tile: contiguous 32 KB per wave, nt float4 ----
        f32x4* __restrict__ outm = reinterpret_cast<f32x4*>(
            out_msgs + (size_t)e * Mc * Dc) + (size_t)r * (32 * 64) + lane;
        const int m0 = r * 32;
#pragma unroll
        for (int k = 0; k < 32; ++k) {
            const float s = (m0 + k < mnum) ? s_score[buf][m0 + k] : 0.0f;
            f32x4 o;
            o.x = s * m4.x; o.y = s * m4.y; o.z = s * m4.z; o.w = s * m4.w;
            __builtin_nontemporal_store(o, outm + (size_t)k * 64);
        }

        __syncthreads();  // all reads of s_score[buf] done; buf^1 visible

        // ---- rotate pipeline state ----
        e = en; cid = cidn; mnum = mlimn; ts = tsn; m4 = m4n; buf ^= 1;
    }
}

extern "C" void kernel_launch(void* const* d_in, const int* in_sizes, int n_in,
                              void* d_out, int out_size, void* d_ws, size_t ws_size,
                              hipStream_t stream) {
    const float* unique_message  = (const float*)d_in[0];
    const float* member_score    = (const float*)d_in[1];
    const float* timestamps      = (const float*)d_in[2];
    const int*   nodes           = (const int*)d_in[3];
    const int*   node2community  = (const int*)d_in[4];
    const int*   community2node  = (const int*)d_in[5];
    const int*   member_num      = (const int*)d_in[6];
    const int*   community_index = (const int*)d_in[7];

    const int B        = in_sizes[2];
    const int N_COMM   = in_sizes[6];
    const int M        = in_sizes[1] / N_COMM;
    const int D        = in_sizes[0] / B;
    const int N_ACTIVE = in_sizes[7];

    float* out_msgs  = (float*)d_out;
    float* out_nodes = out_msgs + (size_t)B * M * D;
    float* out_ts    = out_nodes + (size_t)B * M;

    (void)d_ws; (void)ws_size; (void)n_in; (void)out_size; (void)M; (void)D;

    topk_main_spec<<<B / EPB, 256, 0, stream>>>(
        unique_message, member_score, timestamps, nodes,
        node2community, community2node, member_num,
        community_index, N_ACTIVE,
        out_msgs, out_nodes, out_ts);
}